// Round 10
// baseline (146.771 us; speedup 1.0000x reference)
//
#include <hip/hip_runtime.h>

// ---------------------------------------------------------------------------
// MultiheadSelfAttention: x[2,2048,1024] f32, w_qkv[3072,1024] f32,
// w_out[1024,1024] f32 -> out[2,2048,1024] f32.
// cast->bf16, qkv = x @ w_qkv^T (MFMA), V pre-transpose, causal flash attn
// (32x32 MFMA, swapped ops, in-register softmax + permlane32_swap P redistrib,
// O^T accumulation, 2-wave blocks paired (p,31-p), triple-buffered K/V with
// counted vmcnt), out = ctx @ w_out^T. fp32 accumulation.
// ---------------------------------------------------------------------------

typedef short short8 __attribute__((ext_vector_type(8)));
typedef float f32x4 __attribute__((ext_vector_type(4)));
typedef float f32x16 __attribute__((ext_vector_type(16)));
typedef unsigned int u32x2 __attribute__((ext_vector_type(2)));
typedef unsigned short u16;
typedef unsigned int u32;

#define T_SEQ 2048
#define N_B 2
#define N_H 16
#define HD 64
#define DM 1024
#define TRIPLE 3072

__device__ __forceinline__ u16 f2bf(float f) {
  union { float f; unsigned u; } v;
  v.f = f;
  unsigned r = v.u + 0x7fffu + ((v.u >> 16) & 1u);
  return (u16)(r >> 16);
}

__device__ __forceinline__ float bf2f(u16 x) {
  return __uint_as_float((u32)x << 16);
}

__device__ __forceinline__ u32 cvtpk(float a, float b) {
  u32 r;
  asm("v_cvt_pk_bf16_f32 %0, %1, %2" : "=v"(r) : "v"(a), "v"(b));
  return r;
}

// SSA-safe permlane32_swap: r[0] = {a.row0, b.row0}, r[1] = {a.row1, b.row1}
__device__ __forceinline__ void pl32swap(u32& a, u32& b) {
  u32x2 r = __builtin_amdgcn_permlane32_swap(a, b, false, false);
  a = r[0];
  b = r[1];
}

typedef const __attribute__((address_space(1))) void gvoid;
typedef __attribute__((address_space(3))) void lvoid;

__device__ __forceinline__ void g2l16(const void* g, void* l) {
  __builtin_amdgcn_global_load_lds((gvoid*)g, (lvoid*)l, 16, 0, 0);
}

__device__ __forceinline__ void storeC(float* p, float v) { *p = v; }
__device__ __forceinline__ void storeC(u16* p, float v) { *p = f2bf(v); }

// ---------------------------------------------------------------------------
__global__ __launch_bounds__(256) void cast_all(const float4* __restrict__ x,
                                                const float4* __restrict__ wq,
                                                const float4* __restrict__ wo,
                                                ushort4* __restrict__ out) {
  int i = blockIdx.x * 256 + threadIdx.x;
  const float4* src;
  int off;
  if (i < 1048576) { src = x; off = 0; }
  else if (i < 1835008) { src = wq; off = 1048576; }
  else { src = wo; off = 1835008; }
  float4 v = src[i - off];
  ushort4 o;
  o.x = f2bf(v.x); o.y = f2bf(v.y); o.z = f2bf(v.z); o.w = f2bf(v.w);
  out[i] = o;
}

// ---------------------------------------------------------------------------
// V transpose: qkv[b*T+t][2048 + h*64 + d] -> vT[(b*16+h)*64 + d][t] (bf16).
// ---------------------------------------------------------------------------
__global__ __launch_bounds__(256) void vtrans(const u16* __restrict__ qkv,
                                              u16* __restrict__ vT) {
  const int tid = threadIdx.x;
  const int w = tid >> 6, lane = tid & 63;
  const int ti = lane >> 3, di = lane & 7;
  const int h = blockIdx.y, b = blockIdx.z;
  const int t0 = blockIdx.x * 256 + w * 64 + ti * 8;

  const u16* src = qkv + (size_t)(b * T_SEQ + t0) * TRIPLE + 2 * DM + h * HD + di * 8;
  u32 x[8][4];
#pragma unroll
  for (int e = 0; e < 8; ++e) {
    union { short8 v; u32 u[4]; } cv;
    cv.v = *(const short8*)(src + (size_t)e * TRIPLE);
#pragma unroll
    for (int j = 0; j < 4; ++j) x[e][j] = cv.u[j];
  }
  u32 y[8][4];
#pragma unroll
  for (int a = 0; a < 4; ++a)
#pragma unroll
    for (int j = 0; j < 4; ++j) {
      u32 lo = x[2 * a][j], hi = x[2 * a + 1][j];
      y[2 * a][j] = (lo & 0x0000FFFFu) | (hi << 16);
      y[2 * a + 1][j] = (lo >> 16) | (hi & 0xFFFF0000u);
    }
  u16* dst = vT + ((size_t)(b * N_H + h) * HD + di * 8) * T_SEQ + t0;
#pragma unroll
  for (int dd = 0; dd < 8; ++dd) {
    union { short8 v; u32 u[4]; } cv;
#pragma unroll
    for (int a = 0; a < 4; ++a) cv.u[a] = y[2 * a + (dd & 1)][dd >> 1];
    *(short8*)(dst + (size_t)dd * T_SEQ) = cv.v;
  }
}

// ---------------------------------------------------------------------------
// C[M][N] = A[M][K] * W[N][K]^T  (bf16 in, fp32 acc). 128x128 tile, BK=64.
// ---------------------------------------------------------------------------
template <typename OutT>
__global__ __launch_bounds__(256) void gemm_bt(const u16* __restrict__ A,
                                               const u16* __restrict__ W,
                                               OutT* __restrict__ C,
                                               int M, int N, int K) {
  __shared__ char As[128 * 64 * 2];
  __shared__ char Bs[128 * 64 * 2];
  const int tid = threadIdx.x;
  const int lane = tid & 63, w = tid >> 6;
  const int l15 = lane & 15, l4 = lane >> 4;
  const int m0 = blockIdx.y * 128, n0 = blockIdx.x * 128;
  const int wr = (w >> 1) * 64, wc = (w & 1) * 64;

  const f32x4 zero = {0.f, 0.f, 0.f, 0.f};
  f32x4 acc[4][4];
#pragma unroll
  for (int m = 0; m < 4; ++m)
#pragma unroll
    for (int n = 0; n < 4; ++n) acc[m][n] = zero;

  for (int k0 = 0; k0 < K; k0 += 64) {
#pragma unroll
    for (int i = 0; i < 4; ++i) {
      const int cb = (i * 4 + w) * 64;
      const int c = cb + lane;
      const int row = c >> 3;
      const int ks = ((c & 7) ^ (row & 7)) * 8;
      g2l16(A + (size_t)(m0 + row) * K + k0 + ks, As + (size_t)cb * 16);
      g2l16(W + (size_t)(n0 + row) * K + k0 + ks, Bs + (size_t)cb * 16);
    }
    __syncthreads();

#pragma unroll
    for (int kk = 0; kk < 2; ++kk) {
      short8 a[4], b[4];
#pragma unroll
      for (int m = 0; m < 4; ++m) {
        int row = wr + m * 16 + l15;
        int slot = (kk * 4 + l4) ^ (row & 7);
        a[m] = *(const short8*)(As + row * 128 + slot * 16);
      }
#pragma unroll
      for (int n = 0; n < 4; ++n) {
        int row = wc + n * 16 + l15;
        int slot = (kk * 4 + l4) ^ (row & 7);
        b[n] = *(const short8*)(Bs + row * 128 + slot * 16);
      }
#pragma unroll
      for (int m = 0; m < 4; ++m)
#pragma unroll
        for (int n = 0; n < 4; ++n)
          acc[m][n] = __builtin_amdgcn_mfma_f32_16x16x32_bf16(a[m], b[n], acc[m][n], 0, 0, 0);
    }
    __syncthreads();
  }

#pragma unroll
  for (int m = 0; m < 4; ++m)
#pragma unroll
    for (int n = 0; n < 4; ++n)
#pragma unroll
      for (int r = 0; r < 4; ++r) {
        int row = m0 + wr + m * 16 + l4 * 4 + r;
        int col = n0 + wc + n * 16 + l15;
        storeC(C + (size_t)row * N + col, acc[m][n][r]);
      }
}

// ---------------------------------------------------------------------------
// Causal flash attention, 32x32 MFMA version.
// 2-wave blocks; wave w owns q-rows q0 + 32w .. +31. Paired 64-row q-bands
// (p, 31-p): pass A kt=0..p ascending (diag last), pass B kt=32-i descending
// (diag first) -> 33 iterations per block; per-step working set {i, 32-i}.
// Triple-buffered K/V via global_load_lds, 2-deep prefetch, vmcnt(8) barriers.
// Softmax in-register (q = lane&31); P->PV-B-fragment via cvt_pk +
// permlane32_swap; O accumulated transposed (O^T[d][q]).
// ---------------------------------------------------------------------------
__global__ __launch_bounds__(128) void attn_fwd(const u16* __restrict__ qkv,
                                                const u16* __restrict__ vT,
                                                u16* __restrict__ ctx) {
  __shared__ char Ks[3][8192];   // K tile [64 key][8 slots x16B], slot=c^(key&7)
  __shared__ char Vs[3][8192];   // V^T tile [64 d][8 slots x16B], slot=c^(d&7)

  const int tid = threadIdx.x;
  const int lane = tid & 63, w = tid >> 6;        // 2 waves
  const int l31 = lane & 31, hi = lane >> 5;
  const int g = blockIdx.x;                        // b*16+h (XCD colocation)
  const int p = blockIdx.y;                        // 0..15
  const int h = g & 15, b = g >> 4;
  const int q0A = 64 * p, q0B = 64 * (31 - p);

  // ---- preload Q for both passes, prescaled by 0.125*log2(e) ----
  const float c_log2 = 0.18033688011112042f;
  short8 qa2[2][4];
#pragma unroll
  for (int ps = 0; ps < 2; ++ps) {
    const int qq0 = ps ? q0B : q0A;
    const u16* qp = qkv + (size_t)(b * T_SEQ + qq0 + w * 32 + l31) * TRIPLE + h * HD + hi * 8;
#pragma unroll
    for (int kst = 0; kst < 4; ++kst) {
      short8 raw = *(const short8*)(qp + kst * 16);
      union { short8 v; u32 w4[4]; } qq;
#pragma unroll
      for (int j = 0; j < 4; ++j)
        qq.w4[j] = cvtpk(bf2f((u16)raw[2 * j]) * c_log2,
                         bf2f((u16)raw[2 * j + 1]) * c_log2);
      qa2[ps][kst] = qq.v;
    }
  }

  // ---- staging bases (pre-swizzled source, linear LDS dest) ----
  const int r0 = tid >> 3, c0 = tid & 7;           // r0: 0..15
  const int swz = (c0 ^ (r0 & 7)) << 3;
  const u16* kbase = qkv + (size_t)(b * T_SEQ + r0) * TRIPLE + DM + h * HD + swz;
  const u16* vbase = vT + ((size_t)g * HD + r0) * T_SEQ + swz;

#define STAGE(kt_, buf_)                                                        \
  {                                                                             \
    _Pragma("unroll") for (int i_ = 0; i_ < 4; ++i_) {                          \
      g2l16(kbase + (size_t)((kt_) * 64 + 16 * i_) * TRIPLE,                    \
            Ks[buf_] + tid * 16 + 2048 * i_);                                   \
      g2l16(vbase + (size_t)(16 * i_) * T_SEQ + (kt_) * 64,                     \
            Vs[buf_] + tid * 16 + 2048 * i_);                                   \
    }                                                                           \
  }

  const f32x16 zero16 = {0,0,0,0,0,0,0,0,0,0,0,0,0,0,0,0};
  f32x16 o[2];
  o[0] = zero16; o[1] = zero16;
  float mr = -INFINITY, lr = 0.f;
  short8 qa_0 = qa2[0][0], qa_1 = qa2[0][1], qa_2 = qa2[0][2], qa_3 = qa2[0][3];
  int q0 = q0A;

  // ---- prologue: stage tiles for i=0,1 into bufs 0,1; wait for buf 0 ----
  STAGE(0, 0);
  {
    const int kt1 = (1 <= p) ? 1 : 31;
    STAGE(kt1, 1);
  }
  asm volatile("s_waitcnt vmcnt(8)\n\ts_barrier" ::: "memory");

  int cur = 0;
  for (int i = 0;; ++i) {
    const int kt = (i <= p) ? i : 32 - i;

    // ---- 2-deep prefetch: stage tile for iteration i+2 ----
    if (i + 2 <= 32) {
      const int nkt2 = (i + 2 <= p) ? i + 2 : 30 - i;
      int sb = cur - 1;
      if (sb < 0) sb = 2;
      STAGE(nkt2, sb);
    }

    // ---- S^T = mfma(K, Q): lane holds S[key][q=l31], 2 key-fragments ----
    f32x16 s[2];
    s[0] = zero16; s[1] = zero16;
    __builtin_amdgcn_s_setprio(1);
#pragma unroll
    for (int kst = 0; kst < 4; ++kst) {
      const short8 qa = (kst == 0) ? qa_0 : (kst == 1) ? qa_1 : (kst == 2) ? qa_2 : qa_3;
      const int slot = ((kst * 2 + hi) ^ (l31 & 7)) << 4;
      short8 k0f = *(const short8*)(Ks[cur] + l31 * 128 + slot);
      s[0] = __builtin_amdgcn_mfma_f32_32x32x16_bf16(k0f, qa, s[0], 0, 0, 0);
      short8 k1f = *(const short8*)(Ks[cur] + (32 + l31) * 128 + slot);
      s[1] = __builtin_amdgcn_mfma_f32_32x32x16_bf16(k1f, qa, s[1], 0, 0, 0);
    }
    __builtin_amdgcn_s_setprio(0);

    // ---- causal mask on the two diagonal iterations ----
    if (i == p || i == p + 1) {
      const int qrow = q0 + w * 32 + l31;
      const int kb0 = kt * 64 + 4 * hi;
#pragma unroll
      for (int r = 0; r < 16; ++r) {
        const int key = kb0 + (r & 3) + 8 * (r >> 2);
        if (key > qrow) s[0][r] = -INFINITY;
        if (key + 32 > qrow) s[1][r] = -INFINITY;
      }
    }

    // ---- in-register online softmax (row q = l31), defer-max THR=8 ----
    float tA = fmaxf(s[0][0], s[1][0]);
    float tB = fmaxf(s[0][1], s[1][1]);
    float tC = fmaxf(s[0][2], s[1][2]);
    float tD = fmaxf(s[0][3], s[1][3]);
#pragma unroll
    for (int r = 4; r < 16; r += 4) {
      tA = fmaxf(tA, fmaxf(s[0][r], s[1][r]));
      tB = fmaxf(tB, fmaxf(s[0][r + 1], s[1][r + 1]));
      tC = fmaxf(tC, fmaxf(s[0][r + 2], s[1][r + 2]));
      tD = fmaxf(tD, fmaxf(s[0][r + 3], s[1][r + 3]));
    }
    float mx = fmaxf(fmaxf(tA, tB), fmaxf(tC, tD));
    mx = fmaxf(mx, __shfl_xor(mx, 32));   // cross-half: lane^32 shares q
    if (!__all(mx - mr <= 8.0f)) {
      const float mn = fmaxf(mr, mx);
      const float fr = exp2f(mr - mn);   // 0 on first tile of a pass
      lr *= fr;
#pragma unroll
      for (int r = 0; r < 16; ++r) { o[0][r] *= fr; o[1][r] *= fr; }
      mr = mn;
    }
    {
      float pA = 0.f, pB = 0.f, pC = 0.f, pD = 0.f;
#pragma unroll
      for (int r = 0; r < 16; r += 4) {
        s[0][r] = exp2f(s[0][r] - mr); pA += s[0][r];
        s[0][r + 1] = exp2f(s[0][r + 1] - mr); pB += s[0][r + 1];
        s[0][r + 2] = exp2f(s[0][r + 2] - mr); pC += s[0][r + 2];
        s[0][r + 3] = exp2f(s[0][r + 3] - mr); pD += s[0][r + 3];
        s[1][r] = exp2f(s[1][r] - mr); pA += s[1][r];
        s[1][r + 1] = exp2f(s[1][r + 1] - mr); pB += s[1][r + 1];
        s[1][r + 2] = exp2f(s[1][r + 2] - mr); pC += s[1][r + 2];
        s[1][r + 3] = exp2f(s[1][r + 3] - mr); pD += s[1][r + 3];
      }
      lr += (pA + pB) + (pC + pD);   // per-lane partial (own 32 keys)
    }

    // ---- P -> PV B-fragments in registers: cvt_pk + permlane32_swap ----
    // ---- then PV: O^T[d][q] += mfma(V^T, P) ----
    __builtin_amdgcn_s_setprio(1);
#pragma unroll
    for (int kf = 0; kf < 2; ++kf) {
#pragma unroll
      for (int sub = 0; sub < 2; ++sub) {
        const int base = 8 * sub;
        u32 w00 = cvtpk(s[kf][base + 0], s[kf][base + 1]);
        u32 w01 = cvtpk(s[kf][base + 2], s[kf][base + 3]);
        u32 w10 = cvtpk(s[kf][base + 4], s[kf][base + 5]);
        u32 w11 = cvtpk(s[kf][base + 6], s[kf][base + 7]);
        pl32swap(w00, w10);
        pl32swap(w01, w11);
        union { u32 u[4]; short8 v; } pw;
        pw.u[0] = w00; pw.u[1] = w01; pw.u[2] = w10; pw.u[3] = w11;
        const int ks = kf * 2 + sub;
        const int vslot = (((ks * 2 + hi) ^ (l31 & 7)) << 4);
        short8 v0 = *(const short8*)(Vs[cur] + l31 * 128 + vslot);
        o[0] = __builtin_amdgcn_mfma_f32_32x32x16_bf16(v0, pw.v, o[0], 0, 0, 0);
        short8 v1 = *(const short8*)(Vs[cur] + (32 + l31) * 128 + vslot);
        o[1] = __builtin_amdgcn_mfma_f32_32x32x16_bf16(v1, pw.v, o[1], 0, 0, 0);
      }
    }
    __builtin_amdgcn_s_setprio(0);

    // ---- pass epilogues: write O^T (q = l31 per-lane -> scalar rescale) ----
    if (i == p || i == 32) {
      const float lf = lr + __shfl_xor(lr, 32);
      const float inv = __builtin_amdgcn_rcpf(lf);
      u16* crow = ctx + (size_t)(b * T_SEQ + q0 + w * 32 + l31) * DM + h * HD;
#pragma unroll
      for (int df = 0; df < 2; ++df)
#pragma unroll
        for (int r = 0; r < 16; r += 2) {
          const int d = df * 32 + (r & 3) + 8 * (r >> 2) + 4 * hi;
          u32 pk = cvtpk(o[df][r] * inv, o[df][r + 1] * inv);
          *(u32*)(crow + d) = pk;
        }
      if (i == 32) break;
      // reset for pass B (diag-first, descending)
      o[0] = zero16; o[1] = zero16;
      mr = -INFINITY; lr = 0.f;
      qa_0 = qa2[1][0]; qa_1 = qa2[1][1]; qa_2 = qa2[1][2]; qa_3 = qa2[1][3];
      q0 = q0B;
    }

    // ---- counted-vmcnt barrier: newest stage (8 loads) stays in flight ----
    if (i == 31)
      asm volatile("s_waitcnt vmcnt(0)\n\ts_barrier" ::: "memory");
    else
      asm volatile("s_waitcnt vmcnt(8)\n\ts_barrier" ::: "memory");
    cur = (cur == 2) ? 0 : cur + 1;
  }
#undef STAGE
}

// ---------------------------------------------------------------------------
extern "C" void kernel_launch(void* const* d_in, const int* in_sizes, int n_in,
                              void* d_out, int out_size, void* d_ws, size_t ws_size,
                              hipStream_t stream) {
  const float* x = (const float*)d_in[0];
  const float* wqkv = (const float*)d_in[1];
  const float* wout = (const float*)d_in[2];
  float* out = (float*)d_out;
  char* ws = (char*)d_ws;

  u16* xb    = (u16*)(ws);                       //  8 MB
  u16* wqkvb = (u16*)(ws + 8u * 1024 * 1024);    //  6 MB
  u16* woutb = (u16*)(ws + 14u * 1024 * 1024);   //  2 MB
  u16* qkvb  = (u16*)(ws + 16u * 1024 * 1024);   // 24 MB
  u16* ctxb  = (u16*)(ws + 40u * 1024 * 1024);   //  8 MB
  u16* vTb   = (u16*)(ws + 48u * 1024 * 1024);   //  8 MB

  cast_all<<<8192, 256, 0, stream>>>((const float4*)x, (const float4*)wqkv,
                                     (const float4*)wout, (ushort4*)xb);

  gemm_bt<u16><<<dim3(24, 32), 256, 0, stream>>>(xb, wqkvb, qkvb, 4096, 3072, 1024);

  vtrans<<<dim3(8, N_H, N_B), 256, 0, stream>>>(qkvb, vTb);

  attn_fwd<<<dim3(32, 16), 128, 0, stream>>>(qkvb, vTb, ctxb);

  gemm_bt<float><<<dim3(8, 32), 256, 0, stream>>>(ctxb, woutb, out, 4096, 1024, 1024);
}